// Round 12
// baseline (611.077 us; speedup 1.0000x reference)
//
#include <hip/hip_runtime.h>

// Instant-NGP multires hash encoding fwd. N=1M, L=16, F=2, T=2^19.
// R16 (revert to best R13 @ 242.7us config; R14/R15 aux variants regressed):
//  - Aux: R13's 3-pass fixed-cap scatter, 256 blocks x 1024 thr (best of 7
//    structural variants tried R5-R15).
//  - NEW: non-temporal stores for xs (scat1) and out4 (k_main). Measured
//    write amplification: scat1 57MB written for 16MB payload (3.5x, R14),
//    k_main 187MB for 128MB output (1.46x) — partial 64B lines evicted
//    between 16B sibling stores -> write-allocate RMW. NT skips allocation.
//  - k_main: R13 verbatim otherwise (rolled 8x level-pair loop + SALU
//    integer bounds; 105us, VALUBusy 49%).

__constant__ float c_res[16] = {
    16.f, 18.f, 21.f, 24.f, 27.f, 32.f, 36.f, 42.f,
    48.f, 55.f, 64.f, 73.f, 84.f, 97.f, 111.f, 128.f
};
__constant__ int c_resi[16] = { 16, 18, 21, 24, 27, 32, 36, 42,
                                48, 55, 64, 73, 84, 97, 111, 128 };

#define TMASK   0x7FFFFu
#define PRIME1  2654435761u
#define PRIME2  805459861u
#define NBUCKET 4096          // 16^3 cells
#define NB      256           // scatter blocks
#define NGRP    16            // (Tier B only)
#define CACHE_N 4467          // sum over levels of max corners — exact bound

typedef __attribute__((ext_vector_type(4))) float f32x4;

__device__ __forceinline__ void nt_store4(float4* dst, float4 v) {
    __builtin_nontemporal_store(*(const f32x4*)&v, (f32x4*)dst);
}

__device__ __forceinline__ int bucket_of(float x0, float x1, float x2) {
    // x*16 is EXACT in fp32 (power-of-2 scale), so cell membership is exact.
    int c0 = (int)(x0 * 16.f); c0 = c0 < 0 ? 0 : (c0 > 15 ? 15 : c0);
    int c1 = (int)(x1 * 16.f); c1 = c1 < 0 ? 0 : (c1 > 15 ? 15 : c1);
    int c2 = (int)(x2 * 16.f); c2 = c2 < 0 ? 0 : (c2 > 15 ? 15 : c2);
    return (c0 << 8) | (c1 << 4) | c2;
}

// ---- 3-pass bucket scatter with fixed capacity (R11/R13 form) + NT xs ----
__global__ __launch_bounds__(1024)
void k_scat1(const float* __restrict__ x, unsigned* __restrict__ cnt,
             unsigned* __restrict__ ovfcnt, unsigned* __restrict__ ovfl,
             float4* __restrict__ xs, int npts, int cap, int ovfl_cap)
{
    __shared__ unsigned h[NBUCKET];
    for (int j = threadIdx.x; j < NBUCKET; j += 1024) h[j] = 0u;
    __syncthreads();
    int chunk = (npts + NB - 1) / NB;
    int begin = blockIdx.x * chunk;
    int end   = begin + chunk; if (end > npts) end = npts;

    for (int i = begin + threadIdx.x; i < end; i += 1024) {
        int b = bucket_of(x[3*i], x[3*i+1], x[3*i+2]);
        atomicAdd(&h[b], 1u);                    // LDS atomic
    }
    __syncthreads();
    for (int j = threadIdx.x; j < NBUCKET; j += 1024) {
        unsigned v = h[j];
        if (v) h[j] = atomicAdd(&cnt[j], v);     // reserve [base, base+v)
    }
    __syncthreads();
    for (int i = begin + threadIdx.x; i < end; i += 1024) {
        float x0 = x[3*i], x1 = x[3*i+1], x2 = x[3*i+2];   // L2-hot re-read
        int b = bucket_of(x0, x1, x2);
        unsigned slot = atomicAdd(&h[b], 1u);    // LDS atomic, global slot
        if (slot < (unsigned)cap) {
            float4 v; v.x = x0; v.y = x1; v.z = x2;
            v.w = __uint_as_float((unsigned)i);
            nt_store4(&xs[(size_t)b * cap + slot], v);   // NT: no alloc/RMW
        } else {
            unsigned o = atomicAdd(ovfcnt, 1u);
            if (o < (unsigned)ovfl_cap) ovfl[o] = (unsigned)i;
        }
    }
}

// ---- Tier B aux (R9 path): hist + prefix-rebuild scatter ----
__global__ __launch_bounds__(1024)
void k_histA(const float* __restrict__ x, unsigned* __restrict__ cnt,
             unsigned* __restrict__ grpsum, int npts)
{
    __shared__ unsigned h[NBUCKET];
    for (int j = threadIdx.x; j < NBUCKET; j += 1024) h[j] = 0u;
    __syncthreads();
    int chunk = (npts + NB - 1) / NB;
    int begin = blockIdx.x * chunk;
    int end   = begin + chunk; if (end > npts) end = npts;
    for (int i = begin + threadIdx.x; i < end; i += 1024) {
        int b = bucket_of(x[3 * i], x[3 * i + 1], x[3 * i + 2]);
        atomicAdd(&h[b], 1u);
    }
    __syncthreads();
    unsigned* grow = grpsum + (size_t)(blockIdx.x >> 4) * NBUCKET;
    for (int j = threadIdx.x; j < NBUCKET; j += 1024) {
        unsigned v = h[j];
        cnt[(size_t)blockIdx.x * NBUCKET + j] = v;
        if (v) atomicAdd(&grow[j], v);
    }
}

__global__ __launch_bounds__(1024)
void k_scatB(const float* __restrict__ x, const unsigned* __restrict__ cnt,
             const unsigned* __restrict__ grpsum, unsigned* __restrict__ starts,
             unsigned* __restrict__ perm, int npts)
{
    __shared__ unsigned cur[NBUCKET];
    __shared__ unsigned tmp[1024];
    const int t   = threadIdx.x;
    const int blk = blockIdx.x;
    const int myg = blk >> 4;
    const int r0  = blk & ~15;

    const uint4* gs4 = (const uint4*)grpsum;
    const uint4* ct4 = (const uint4*)cnt;
    uint4 tot = make_uint4(0u,0u,0u,0u), bas = make_uint4(0u,0u,0u,0u);
    #pragma unroll
    for (int g = 0; g < NGRP; ++g) {
        uint4 v = gs4[g * 1024 + t];
        tot.x += v.x; tot.y += v.y; tot.z += v.z; tot.w += v.w;
        if (g < myg) { bas.x += v.x; bas.y += v.y; bas.z += v.z; bas.w += v.w; }
    }
    for (int r = r0; r < blk; ++r) {
        uint4 v = ct4[r * 1024 + t];
        bas.x += v.x; bas.y += v.y; bas.z += v.z; bas.w += v.w;
    }
    unsigned s = tot.x + tot.y + tot.z + tot.w;
    tmp[t] = s;
    __syncthreads();
    for (int off = 1; off < 1024; off <<= 1) {
        unsigned u = (t >= off) ? tmp[t - off] : 0u;
        __syncthreads();
        tmp[t] += u;
        __syncthreads();
    }
    unsigned excl = tmp[t] - s;
    unsigned s0 = excl, s1 = s0 + tot.x, s2 = s1 + tot.y, s3 = s2 + tot.z;
    cur[4*t+0] = s0 + bas.x;
    cur[4*t+1] = s1 + bas.y;
    cur[4*t+2] = s2 + bas.z;
    cur[4*t+3] = s3 + bas.w;
    if (blk == 0) {
        starts[4*t+0] = s0; starts[4*t+1] = s1;
        starts[4*t+2] = s2; starts[4*t+3] = s3;
        if (t == 1023) starts[NBUCKET] = tmp[1023];
    }
    __syncthreads();

    int chunk = (npts + NB - 1) / NB;
    int begin = blk * chunk;
    int end   = begin + chunk; if (end > npts) end = npts;
    for (int i = begin + t; i < end; i += 1024) {
        float x0 = x[3 * i], x1 = x[3 * i + 1], x2 = x[3 * i + 2];
        int b = bucket_of(x0, x1, x2);
        unsigned pos = atomicAdd(&cur[b], 1u);
        perm[pos] = (unsigned)i;
    }
}

// ---- per-point direct evaluation (overflow tail) ----
__device__ __forceinline__ void point_direct(const float* __restrict__ x,
                                             const float2* __restrict__ tab,
                                             float4* __restrict__ out4,
                                             unsigned p)
{
    float a0 = x[3*p], a1 = x[3*p+1], a2 = x[3*p+2];
    #pragma unroll 1
    for (int lp = 0; lp < 8; ++lp) {
        float4 o;
        #pragma unroll
        for (int half = 0; half < 2; ++half) {
            int l = 2 * lp + half;
            float r = c_res[l];
            float s0 = a0 * r, s1 = a1 * r, s2 = a2 * r;
            float f0 = floorf(s0), f1 = floorf(s1), f2 = floorf(s2);
            float d0 = s0 - f0, d1 = s1 - f1, d2 = s2 - f2;
            unsigned A0 = (unsigned)(int)f0, B0 = (unsigned)(int)ceilf(s0);
            unsigned A1 = (unsigned)(int)f1 * PRIME1,
                     B1 = (unsigned)(int)ceilf(s1) * PRIME1;
            unsigned A2 = (unsigned)(int)f2 * PRIME2,
                     B2 = (unsigned)(int)ceilf(s2) * PRIME2;
            float2 v0 = tab[(A0^A1^A2)&TMASK], v1 = tab[(B0^A1^A2)&TMASK];
            float2 v2 = tab[(A0^B1^A2)&TMASK], v3 = tab[(A0^A1^B2)&TMASK];
            float2 v4 = tab[(B0^B1^A2)&TMASK], v5 = tab[(B0^A1^B2)&TMASK];
            float2 v6 = tab[(A0^B1^B2)&TMASK], v7 = tab[(B0^B1^B2)&TMASK];
            float u0 = 1.f-d0, u1 = 1.f-d1, u2 = 1.f-d2;
            float ex = v0.x*(u0*u1*u2), ey = v0.y*(u0*u1*u2);
            ex += v1.x*(d0*u1*u2); ey += v1.y*(d0*u1*u2);
            ex += v2.x*(u0*d1*u2); ey += v2.y*(u0*d1*u2);
            ex += v3.x*(u0*u1*d2); ey += v3.y*(u0*u1*d2);
            ex += v4.x*(d0*d1*u2); ey += v4.y*(d0*d1*u2);
            ex += v5.x*(d0*u1*d2); ey += v5.y*(d0*u1*d2);
            ex += v6.x*(u0*d1*d2); ey += v6.y*(u0*d1*d2);
            ex += v7.x*(d0*d1*d2); ey += v7.y*(d0*d1*d2);
            if (half) { o.z = ex; o.w = ey; } else { o.x = ex; o.y = ey; }
        }
        out4[(size_t)p * 8 + lp] = o;
    }
}

// ---- main: per-cell LDS corner cache; ROLLED loop + SALU integer bounds ----
// lo=(c*R)>>4, hi=((c+1)*R+15)>>4 — exact (dyadic argument; refcheck'd R12).

template<int MODE>   // 0: fixed-cap xs + cnt.  1: perm + scattered x + starts
__global__ __launch_bounds__(512, 8)
void k_main(const float4* __restrict__ xs, const float* __restrict__ x,
            const unsigned* __restrict__ perm,
            const unsigned* __restrict__ starts, const float2* __restrict__ tab,
            float4* __restrict__ out4, const unsigned* __restrict__ cnt,
            const unsigned* __restrict__ ovfcnt,
            const unsigned* __restrict__ ovfl, int cap, int ovfl_cap)
{
    __shared__ float2 cache[CACHE_N];

    int cell = blockIdx.x;
    int startp, endp;
    if constexpr (MODE == 0) {
        unsigned cn = cnt[cell];
        if (cn > (unsigned)cap) cn = (unsigned)cap;
        startp = cell * cap;
        endp   = startp + (int)cn;
    } else {
        startp = starts[cell]; endp = starts[cell + 1];
    }

    if (startp < endp) {
        const int ci = (cell >> 8) & 15, cj = (cell >> 4) & 15, ck = cell & 15;

        // ---- loader: all 512 threads, each unique corner gathered once ----
        {
            int cbase = 0;
            #pragma unroll 1
            for (int l = 0; l < 16; ++l) {
                const int RI = c_resi[l];
                int lo0 = (ci * RI) >> 4, hi0 = ((ci + 1) * RI + 15) >> 4;
                int lo1 = (cj * RI) >> 4, hi1 = ((cj + 1) * RI + 15) >> 4;
                int lo2 = (ck * RI) >> 4, hi2 = ((ck + 1) * RI + 15) >> 4;
                int n1 = hi1 - lo1 + 1, n2 = hi2 - lo2 + 1;
                int n12 = n1 * n2, tot = (hi0 - lo0 + 1) * n12;
                for (int t = threadIdx.x; t < tot; t += 512) {
                    int a = t / n12, rem = t - a * n12;
                    int b = rem / n2, d = rem - b * n2;
                    unsigned hh = ((unsigned)(lo0 + a)
                                ^ ((unsigned)(lo1 + b) * PRIME1)
                                ^ ((unsigned)(lo2 + d) * PRIME2)) & TMASK;
                    cache[cbase + t] = tab[hh];
                }
                cbase += tot;
            }
        }
        __syncthreads();

        for (int sp = startp + (int)threadIdx.x; sp < endp; sp += 512) {
            float x0, x1, x2; unsigned p;
            if constexpr (MODE == 0) {
                float4 v = xs[sp];
                x0 = v.x; x1 = v.y; x2 = v.z; p = __float_as_uint(v.w);
            } else {
                p = perm[sp];
                x0 = x[3 * p]; x1 = x[3 * p + 1]; x2 = x[3 * p + 2];
            }
            // one thread writes the point's whole 128B row, contiguously;
            // level loop stays ROLLED (8 pairs) — small body, no spill.
            int cbase = 0;
            #pragma unroll 1
            for (int lp = 0; lp < 8; ++lp) {
                float4 o;
                #pragma unroll
                for (int half = 0; half < 2; ++half) {
                    const int l = 2 * lp + half;
                    const int RI = c_resi[l];        // K-cache s_load, uniform
                    // wave-uniform SALU bounds (replaces metaA/metaB LDS)
                    int lo0 = (ci * RI) >> 4, hi0 = ((ci + 1) * RI + 15) >> 4;
                    int lo1 = (cj * RI) >> 4, hi1 = ((cj + 1) * RI + 15) >> 4;
                    int lo2 = (ck * RI) >> 4, hi2 = ((ck + 1) * RI + 15) >> 4;
                    int n1 = hi1 - lo1 + 1, n2 = hi2 - lo2 + 1;
                    int n12 = n1 * n2;
                    int tot = (hi0 - lo0 + 1) * n12;
                    float r = c_res[l];

                    float s0 = x0 * r, s1 = x1 * r, s2 = x2 * r;  // == numpy
                    float f0 = floorf(s0), f1 = floorf(s1), f2 = floorf(s2);
                    float d0 = s0 - f0, d1 = s1 - f1, d2 = s2 - f2;
                    int A0 = (int)f0 - lo0, A1 = (int)f1 - lo1,
                        A2 = (int)f2 - lo2;
                    // ceil(s) = floor(s) + (s != floor(s)) for s >= 0
                    int e0 = (d0 != 0.f) ? n12 : 0;
                    int e1 = (d1 != 0.f) ? n2  : 0;
                    int e2 = (d2 != 0.f) ? 1   : 0;
                    int rA = cbase + A0 * n12 + A1 * n2 + A2;

                    float2 v0 = cache[rA];                 // 000
                    float2 v1 = cache[rA + e0];            // 100
                    float2 v2 = cache[rA + e1];            // 010
                    float2 v3 = cache[rA + e2];            // 001
                    float2 v4 = cache[rA + e0 + e1];       // 110
                    float2 v5 = cache[rA + e0 + e2];       // 101
                    float2 v6 = cache[rA + e1 + e2];       // 011
                    float2 v7 = cache[rA + e0 + e1 + e2];  // 111

                    float u0 = 1.f - d0, u1 = 1.f - d1, u2 = 1.f - d2;
                    float pa = u1 * u2, pb = d1 * u2, pc = u1 * d2,
                          pe = d1 * d2;
                    float w0 = u0 * pa, w1 = d0 * pa, w2 = u0 * pb,
                          w3 = u0 * pc;
                    float w4 = d0 * pb, w5 = d0 * pc, w6 = u0 * pe,
                          w7 = d0 * pe;

                    float rx = v0.x * w0, ry = v0.y * w0;
                    rx += v1.x * w1;  ry += v1.y * w1;
                    rx += v2.x * w2;  ry += v2.y * w2;
                    rx += v3.x * w3;  ry += v3.y * w3;
                    rx += v4.x * w4;  ry += v4.y * w4;
                    rx += v5.x * w5;  ry += v5.y * w5;
                    rx += v6.x * w6;  ry += v6.y * w6;
                    rx += v7.x * w7;  ry += v7.y * w7;

                    if (half) { o.z = rx; o.w = ry; }
                    else      { o.x = rx; o.y = ry; }
                    cbase += tot;
                }
                nt_store4(&out4[(size_t)p * 8 + lp], o);  // NT: no alloc/RMW
            }
        }
    }

    // ---- overflow tail (MODE 0): ~zero cost when empty ----
    if constexpr (MODE == 0) {
        unsigned ovfn = *ovfcnt;
        if (ovfn > (unsigned)ovfl_cap) ovfn = (unsigned)ovfl_cap;
        for (unsigned u = blockIdx.x * 512u + threadIdx.x; u < ovfn;
             u += 4096u * 512u)
            point_direct(x, tab, out4, ovfl[u]);
    }
}

// Fallback (R1) if ws too small.
__global__ __launch_bounds__(256, 8)
void k_fallback(const float* __restrict__ x, const float2* __restrict__ tab,
                float2* __restrict__ out, int total) {
    int tid = blockIdx.x * 256 + threadIdx.x;
    if (tid >= total) return;
    int p = tid >> 4, l = tid & 15;
    float r = c_res[l];
    float s0 = x[3*p] * r, s1 = x[3*p+1] * r, s2 = x[3*p+2] * r;
    float f0 = floorf(s0), f1 = floorf(s1), f2 = floorf(s2);
    float d0 = s0 - f0, d1 = s1 - f1, d2 = s2 - f2;
    unsigned A0 = (unsigned)(int)f0, B0 = (unsigned)(int)ceilf(s0);
    unsigned A1 = (unsigned)(int)f1 * PRIME1, B1 = (unsigned)(int)ceilf(s1) * PRIME1;
    unsigned A2 = (unsigned)(int)f2 * PRIME2, B2 = (unsigned)(int)ceilf(s2) * PRIME2;
    unsigned h0=(A0^A1^A2)&TMASK, h1=(B0^A1^A2)&TMASK, h2=(A0^B1^A2)&TMASK;
    unsigned h3=(A0^A1^B2)&TMASK, h4=(B0^B1^A2)&TMASK, h5=(B0^A1^B2)&TMASK;
    unsigned h6=(A0^B1^B2)&TMASK, h7=(B0^B1^B2)&TMASK;
    float2 v0=tab[h0],v1=tab[h1],v2=tab[h2],v3=tab[h3];
    float2 v4=tab[h4],v5=tab[h5],v6=tab[h6],v7=tab[h7];
    float u0=1.f-d0,u1=1.f-d1,u2=1.f-d2;
    float ex = v0.x*(u0*u1*u2), ey = v0.y*(u0*u1*u2);
    ex += v1.x*(d0*u1*u2); ey += v1.y*(d0*u1*u2);
    ex += v2.x*(u0*d1*u2); ey += v2.y*(u0*d1*u2);
    ex += v3.x*(u0*u1*d2); ey += v3.y*(u0*u1*d2);
    ex += v4.x*(d0*d1*u2); ey += v4.y*(d0*d1*u2);
    ex += v5.x*(d0*u1*d2); ey += v5.y*(d0*u1*d2);
    ex += v6.x*(u0*d1*d2); ey += v6.y*(u0*d1*d2);
    ex += v7.x*(d0*d1*d2); ey += v7.y*(d0*d1*d2);
    float2 o; o.x = ex; o.y = ey; out[tid] = o;
}

extern "C" void kernel_launch(void* const* d_in, const int* in_sizes, int n_in,
                              void* d_out, int out_size, void* d_ws, size_t ws_size,
                              hipStream_t stream)
{
    const float*  x   = (const float*)d_in[0];
    const float2* tab = (const float2*)d_in[1];
    int npts = in_sizes[0] / 3;

    // ---- Tier A: fixed-capacity buckets, 1 aux kernel ----
    {
        size_t off_cnt  = 0;                                       // 16 KB
        size_t off_ovfc = off_cnt + (size_t)NBUCKET * 4;           // 64 B slot
        size_t off_ovfl = (off_ovfc + 64 + 63) & ~(size_t)63;      // npts*4
        size_t off_xs   = (off_ovfl + (size_t)npts * 4 + 255) & ~(size_t)255;
        if (ws_size > off_xs) {
            size_t avail = ws_size - off_xs;
            long long capll = (long long)(avail / ((size_t)NBUCKET * 16));
            int cap = (int)(capll > 512 ? 512 : capll);
            int mean = npts / NBUCKET + 1;
            if (cap >= mean + (mean + 3) / 4 + 64) {
                unsigned* cnt    = (unsigned*)((char*)d_ws + off_cnt);
                unsigned* ovfc   = (unsigned*)((char*)d_ws + off_ovfc);
                unsigned* ovfl   = (unsigned*)((char*)d_ws + off_ovfl);
                float4*   xs     = (float4*)  ((char*)d_ws + off_xs);

                hipMemsetAsync((char*)d_ws + off_cnt, 0,
                               (size_t)NBUCKET * 4 + 64, stream);
                k_scat1 <<<NB, 1024, 0, stream>>>(x, cnt, ovfc, ovfl, xs,
                                                  npts, cap, npts);
                k_main<0><<<NBUCKET, 512, 0, stream>>>(xs, x, nullptr, nullptr,
                                                       tab, (float4*)d_out,
                                                       cnt, ovfc, ovfl,
                                                       cap, npts);
                return;
            }
        }
    }

    // ---- Tier B: perm-only path (R9, ~8.3 MB ws) ----
    {
        size_t off_grpsum = 0;                                        // 256 KB
        size_t off_cnt    = off_grpsum + (size_t)NGRP * NBUCKET * 4;  // 4 MB
        size_t off_starts = off_cnt    + (size_t)NB * NBUCKET * 4;
        size_t off_perm   = (off_starts + (size_t)(NBUCKET + 1) * 4 + 63)
                            & ~(size_t)63;
        size_t need       = off_perm + (size_t)npts * 4;
        if (ws_size >= need) {
            unsigned* grpsum = (unsigned*)((char*)d_ws + off_grpsum);
            unsigned* cnt    = (unsigned*)((char*)d_ws + off_cnt);
            unsigned* starts = (unsigned*)((char*)d_ws + off_starts);
            unsigned* perm   = (unsigned*)((char*)d_ws + off_perm);

            hipMemsetAsync(grpsum, 0, (size_t)NGRP * NBUCKET * 4, stream);
            k_histA   <<<NB, 1024, 0, stream>>>(x, cnt, grpsum, npts);
            k_scatB   <<<NB, 1024, 0, stream>>>(x, cnt, grpsum, starts,
                                                perm, npts);
            k_main<1> <<<NBUCKET, 512, 0, stream>>>(nullptr, x, perm, starts,
                                                    tab, (float4*)d_out,
                                                    nullptr, nullptr, nullptr,
                                                    0, 0);
            return;
        }
    }

    // ---- fallback ----
    int total = npts * 16;
    k_fallback<<<(total + 255) / 256, 256, 0, stream>>>(
        x, tab, (float2*)d_out, total);
}

// Round 14
// 242.566 us; speedup vs baseline: 2.5192x; 2.5192x over previous
//
#include <hip/hip_runtime.h>

// Instant-NGP multires hash encoding fwd. N=1M, L=16, F=2, T=2^19.
// R18 = resubmit of R17 (pure R13 revert, 242.7us) — round 13's bench failed
// on container acquisition, not on the kernel. No source change.
//  - R16's nontemporal stores were poison on gfx950: L2 write-back IS the
//    write combiner; nt 16B stores -> 3.5x write traffic, k_main 105->446us.
//  - Aux: 3-pass fixed-cap scatter, 256 blocks x 1024 thr (best of 8
//    structural variants, R5-R16). k_main: rolled 8x level-pair loop + SALU
//    integer bounds (105us, VALUBusy 49%).
//  - Both pre-registered falsifiers (R15 atomic-locality, R16 nt-stores)
//    fired; if this lands ~242 the decomposition floor is confirmed.

__constant__ float c_res[16] = {
    16.f, 18.f, 21.f, 24.f, 27.f, 32.f, 36.f, 42.f,
    48.f, 55.f, 64.f, 73.f, 84.f, 97.f, 111.f, 128.f
};
__constant__ int c_resi[16] = { 16, 18, 21, 24, 27, 32, 36, 42,
                                48, 55, 64, 73, 84, 97, 111, 128 };

#define TMASK   0x7FFFFu
#define PRIME1  2654435761u
#define PRIME2  805459861u
#define NBUCKET 4096          // 16^3 cells
#define NB      256           // scatter blocks
#define NGRP    16            // (Tier B only)
#define CACHE_N 4467          // sum over levels of max corners — exact bound

__device__ __forceinline__ int bucket_of(float x0, float x1, float x2) {
    // x*16 is EXACT in fp32 (power-of-2 scale), so cell membership is exact.
    int c0 = (int)(x0 * 16.f); c0 = c0 < 0 ? 0 : (c0 > 15 ? 15 : c0);
    int c1 = (int)(x1 * 16.f); c1 = c1 < 0 ? 0 : (c1 > 15 ? 15 : c1);
    int c2 = (int)(x2 * 16.f); c2 = c2 < 0 ? 0 : (c2 > 15 ? 15 : c2);
    return (c0 << 8) | (c1 << 4) | c2;
}

// ---- 3-pass bucket scatter with fixed capacity (R11/R13 form) ----
__global__ __launch_bounds__(1024)
void k_scat1(const float* __restrict__ x, unsigned* __restrict__ cnt,
             unsigned* __restrict__ ovfcnt, unsigned* __restrict__ ovfl,
             float4* __restrict__ xs, int npts, int cap, int ovfl_cap)
{
    __shared__ unsigned h[NBUCKET];
    for (int j = threadIdx.x; j < NBUCKET; j += 1024) h[j] = 0u;
    __syncthreads();
    int chunk = (npts + NB - 1) / NB;
    int begin = blockIdx.x * chunk;
    int end   = begin + chunk; if (end > npts) end = npts;

    for (int i = begin + threadIdx.x; i < end; i += 1024) {
        int b = bucket_of(x[3*i], x[3*i+1], x[3*i+2]);
        atomicAdd(&h[b], 1u);                    // LDS atomic
    }
    __syncthreads();
    for (int j = threadIdx.x; j < NBUCKET; j += 1024) {
        unsigned v = h[j];
        if (v) h[j] = atomicAdd(&cnt[j], v);     // reserve [base, base+v)
    }
    __syncthreads();
    for (int i = begin + threadIdx.x; i < end; i += 1024) {
        float x0 = x[3*i], x1 = x[3*i+1], x2 = x[3*i+2];   // L2-hot re-read
        int b = bucket_of(x0, x1, x2);
        unsigned slot = atomicAdd(&h[b], 1u);    // LDS atomic, global slot
        if (slot < (unsigned)cap) {
            float4 v; v.x = x0; v.y = x1; v.z = x2;
            v.w = __uint_as_float((unsigned)i);
            xs[(size_t)b * cap + slot] = v;
        } else {
            unsigned o = atomicAdd(ovfcnt, 1u);
            if (o < (unsigned)ovfl_cap) ovfl[o] = (unsigned)i;
        }
    }
}

// ---- Tier B aux (R9 path): hist + prefix-rebuild scatter ----
__global__ __launch_bounds__(1024)
void k_histA(const float* __restrict__ x, unsigned* __restrict__ cnt,
             unsigned* __restrict__ grpsum, int npts)
{
    __shared__ unsigned h[NBUCKET];
    for (int j = threadIdx.x; j < NBUCKET; j += 1024) h[j] = 0u;
    __syncthreads();
    int chunk = (npts + NB - 1) / NB;
    int begin = blockIdx.x * chunk;
    int end   = begin + chunk; if (end > npts) end = npts;
    for (int i = begin + threadIdx.x; i < end; i += 1024) {
        int b = bucket_of(x[3 * i], x[3 * i + 1], x[3 * i + 2]);
        atomicAdd(&h[b], 1u);
    }
    __syncthreads();
    unsigned* grow = grpsum + (size_t)(blockIdx.x >> 4) * NBUCKET;
    for (int j = threadIdx.x; j < NBUCKET; j += 1024) {
        unsigned v = h[j];
        cnt[(size_t)blockIdx.x * NBUCKET + j] = v;
        if (v) atomicAdd(&grow[j], v);
    }
}

__global__ __launch_bounds__(1024)
void k_scatB(const float* __restrict__ x, const unsigned* __restrict__ cnt,
             const unsigned* __restrict__ grpsum, unsigned* __restrict__ starts,
             unsigned* __restrict__ perm, int npts)
{
    __shared__ unsigned cur[NBUCKET];
    __shared__ unsigned tmp[1024];
    const int t   = threadIdx.x;
    const int blk = blockIdx.x;
    const int myg = blk >> 4;
    const int r0  = blk & ~15;

    const uint4* gs4 = (const uint4*)grpsum;
    const uint4* ct4 = (const uint4*)cnt;
    uint4 tot = make_uint4(0u,0u,0u,0u), bas = make_uint4(0u,0u,0u,0u);
    #pragma unroll
    for (int g = 0; g < NGRP; ++g) {
        uint4 v = gs4[g * 1024 + t];
        tot.x += v.x; tot.y += v.y; tot.z += v.z; tot.w += v.w;
        if (g < myg) { bas.x += v.x; bas.y += v.y; bas.z += v.z; bas.w += v.w; }
    }
    for (int r = r0; r < blk; ++r) {
        uint4 v = ct4[r * 1024 + t];
        bas.x += v.x; bas.y += v.y; bas.z += v.z; bas.w += v.w;
    }
    unsigned s = tot.x + tot.y + tot.z + tot.w;
    tmp[t] = s;
    __syncthreads();
    for (int off = 1; off < 1024; off <<= 1) {
        unsigned u = (t >= off) ? tmp[t - off] : 0u;
        __syncthreads();
        tmp[t] += u;
        __syncthreads();
    }
    unsigned excl = tmp[t] - s;
    unsigned s0 = excl, s1 = s0 + tot.x, s2 = s1 + tot.y, s3 = s2 + tot.z;
    cur[4*t+0] = s0 + bas.x;
    cur[4*t+1] = s1 + bas.y;
    cur[4*t+2] = s2 + bas.z;
    cur[4*t+3] = s3 + bas.w;
    if (blk == 0) {
        starts[4*t+0] = s0; starts[4*t+1] = s1;
        starts[4*t+2] = s2; starts[4*t+3] = s3;
        if (t == 1023) starts[NBUCKET] = tmp[1023];
    }
    __syncthreads();

    int chunk = (npts + NB - 1) / NB;
    int begin = blk * chunk;
    int end   = begin + chunk; if (end > npts) end = npts;
    for (int i = begin + t; i < end; i += 1024) {
        float x0 = x[3 * i], x1 = x[3 * i + 1], x2 = x[3 * i + 2];
        int b = bucket_of(x0, x1, x2);
        unsigned pos = atomicAdd(&cur[b], 1u);
        perm[pos] = (unsigned)i;
    }
}

// ---- per-point direct evaluation (overflow tail) ----
__device__ __forceinline__ void point_direct(const float* __restrict__ x,
                                             const float2* __restrict__ tab,
                                             float4* __restrict__ out4,
                                             unsigned p)
{
    float a0 = x[3*p], a1 = x[3*p+1], a2 = x[3*p+2];
    #pragma unroll 1
    for (int lp = 0; lp < 8; ++lp) {
        float4 o;
        #pragma unroll
        for (int half = 0; half < 2; ++half) {
            int l = 2 * lp + half;
            float r = c_res[l];
            float s0 = a0 * r, s1 = a1 * r, s2 = a2 * r;
            float f0 = floorf(s0), f1 = floorf(s1), f2 = floorf(s2);
            float d0 = s0 - f0, d1 = s1 - f1, d2 = s2 - f2;
            unsigned A0 = (unsigned)(int)f0, B0 = (unsigned)(int)ceilf(s0);
            unsigned A1 = (unsigned)(int)f1 * PRIME1,
                     B1 = (unsigned)(int)ceilf(s1) * PRIME1;
            unsigned A2 = (unsigned)(int)f2 * PRIME2,
                     B2 = (unsigned)(int)ceilf(s2) * PRIME2;
            float2 v0 = tab[(A0^A1^A2)&TMASK], v1 = tab[(B0^A1^A2)&TMASK];
            float2 v2 = tab[(A0^B1^A2)&TMASK], v3 = tab[(A0^A1^B2)&TMASK];
            float2 v4 = tab[(B0^B1^A2)&TMASK], v5 = tab[(B0^A1^B2)&TMASK];
            float2 v6 = tab[(A0^B1^B2)&TMASK], v7 = tab[(B0^B1^B2)&TMASK];
            float u0 = 1.f-d0, u1 = 1.f-d1, u2 = 1.f-d2;
            float ex = v0.x*(u0*u1*u2), ey = v0.y*(u0*u1*u2);
            ex += v1.x*(d0*u1*u2); ey += v1.y*(d0*u1*u2);
            ex += v2.x*(u0*d1*u2); ey += v2.y*(u0*d1*u2);
            ex += v3.x*(u0*u1*d2); ey += v3.y*(u0*u1*d2);
            ex += v4.x*(d0*d1*u2); ey += v4.y*(d0*d1*u2);
            ex += v5.x*(d0*u1*d2); ey += v5.y*(d0*u1*d2);
            ex += v6.x*(u0*d1*d2); ey += v6.y*(u0*d1*d2);
            ex += v7.x*(d0*d1*d2); ey += v7.y*(d0*d1*d2);
            if (half) { o.z = ex; o.w = ey; } else { o.x = ex; o.y = ey; }
        }
        out4[(size_t)p * 8 + lp] = o;
    }
}

// ---- main: per-cell LDS corner cache; ROLLED loop + SALU integer bounds ----
// lo=(c*R)>>4, hi=((c+1)*R+15)>>4 — exact (dyadic argument; refcheck'd R12).

template<int MODE>   // 0: fixed-cap xs + cnt.  1: perm + scattered x + starts
__global__ __launch_bounds__(512, 8)
void k_main(const float4* __restrict__ xs, const float* __restrict__ x,
            const unsigned* __restrict__ perm,
            const unsigned* __restrict__ starts, const float2* __restrict__ tab,
            float4* __restrict__ out4, const unsigned* __restrict__ cnt,
            const unsigned* __restrict__ ovfcnt,
            const unsigned* __restrict__ ovfl, int cap, int ovfl_cap)
{
    __shared__ float2 cache[CACHE_N];

    int cell = blockIdx.x;
    int startp, endp;
    if constexpr (MODE == 0) {
        unsigned cn = cnt[cell];
        if (cn > (unsigned)cap) cn = (unsigned)cap;
        startp = cell * cap;
        endp   = startp + (int)cn;
    } else {
        startp = starts[cell]; endp = starts[cell + 1];
    }

    if (startp < endp) {
        const int ci = (cell >> 8) & 15, cj = (cell >> 4) & 15, ck = cell & 15;

        // ---- loader: all 512 threads, each unique corner gathered once ----
        {
            int cbase = 0;
            #pragma unroll 1
            for (int l = 0; l < 16; ++l) {
                const int RI = c_resi[l];
                int lo0 = (ci * RI) >> 4, hi0 = ((ci + 1) * RI + 15) >> 4;
                int lo1 = (cj * RI) >> 4, hi1 = ((cj + 1) * RI + 15) >> 4;
                int lo2 = (ck * RI) >> 4, hi2 = ((ck + 1) * RI + 15) >> 4;
                int n1 = hi1 - lo1 + 1, n2 = hi2 - lo2 + 1;
                int n12 = n1 * n2, tot = (hi0 - lo0 + 1) * n12;
                for (int t = threadIdx.x; t < tot; t += 512) {
                    int a = t / n12, rem = t - a * n12;
                    int b = rem / n2, d = rem - b * n2;
                    unsigned hh = ((unsigned)(lo0 + a)
                                ^ ((unsigned)(lo1 + b) * PRIME1)
                                ^ ((unsigned)(lo2 + d) * PRIME2)) & TMASK;
                    cache[cbase + t] = tab[hh];
                }
                cbase += tot;
            }
        }
        __syncthreads();

        for (int sp = startp + (int)threadIdx.x; sp < endp; sp += 512) {
            float x0, x1, x2; unsigned p;
            if constexpr (MODE == 0) {
                float4 v = xs[sp];
                x0 = v.x; x1 = v.y; x2 = v.z; p = __float_as_uint(v.w);
            } else {
                p = perm[sp];
                x0 = x[3 * p]; x1 = x[3 * p + 1]; x2 = x[3 * p + 2];
            }
            // one thread writes the point's whole 128B row, contiguously;
            // level loop stays ROLLED (8 pairs) — small body, no spill.
            int cbase = 0;
            #pragma unroll 1
            for (int lp = 0; lp < 8; ++lp) {
                float4 o;
                #pragma unroll
                for (int half = 0; half < 2; ++half) {
                    const int l = 2 * lp + half;
                    const int RI = c_resi[l];        // K-cache s_load, uniform
                    // wave-uniform SALU bounds (replaces metaA/metaB LDS)
                    int lo0 = (ci * RI) >> 4, hi0 = ((ci + 1) * RI + 15) >> 4;
                    int lo1 = (cj * RI) >> 4, hi1 = ((cj + 1) * RI + 15) >> 4;
                    int lo2 = (ck * RI) >> 4, hi2 = ((ck + 1) * RI + 15) >> 4;
                    int n1 = hi1 - lo1 + 1, n2 = hi2 - lo2 + 1;
                    int n12 = n1 * n2;
                    int tot = (hi0 - lo0 + 1) * n12;
                    float r = c_res[l];

                    float s0 = x0 * r, s1 = x1 * r, s2 = x2 * r;  // == numpy
                    float f0 = floorf(s0), f1 = floorf(s1), f2 = floorf(s2);
                    float d0 = s0 - f0, d1 = s1 - f1, d2 = s2 - f2;
                    int A0 = (int)f0 - lo0, A1 = (int)f1 - lo1,
                        A2 = (int)f2 - lo2;
                    // ceil(s) = floor(s) + (s != floor(s)) for s >= 0
                    int e0 = (d0 != 0.f) ? n12 : 0;
                    int e1 = (d1 != 0.f) ? n2  : 0;
                    int e2 = (d2 != 0.f) ? 1   : 0;
                    int rA = cbase + A0 * n12 + A1 * n2 + A2;

                    float2 v0 = cache[rA];                 // 000
                    float2 v1 = cache[rA + e0];            // 100
                    float2 v2 = cache[rA + e1];            // 010
                    float2 v3 = cache[rA + e2];            // 001
                    float2 v4 = cache[rA + e0 + e1];       // 110
                    float2 v5 = cache[rA + e0 + e2];       // 101
                    float2 v6 = cache[rA + e1 + e2];       // 011
                    float2 v7 = cache[rA + e0 + e1 + e2];  // 111

                    float u0 = 1.f - d0, u1 = 1.f - d1, u2 = 1.f - d2;
                    float pa = u1 * u2, pb = d1 * u2, pc = u1 * d2,
                          pe = d1 * d2;
                    float w0 = u0 * pa, w1 = d0 * pa, w2 = u0 * pb,
                          w3 = u0 * pc;
                    float w4 = d0 * pb, w5 = d0 * pc, w6 = u0 * pe,
                          w7 = d0 * pe;

                    float rx = v0.x * w0, ry = v0.y * w0;
                    rx += v1.x * w1;  ry += v1.y * w1;
                    rx += v2.x * w2;  ry += v2.y * w2;
                    rx += v3.x * w3;  ry += v3.y * w3;
                    rx += v4.x * w4;  ry += v4.y * w4;
                    rx += v5.x * w5;  ry += v5.y * w5;
                    rx += v6.x * w6;  ry += v6.y * w6;
                    rx += v7.x * w7;  ry += v7.y * w7;

                    if (half) { o.z = rx; o.w = ry; }
                    else      { o.x = rx; o.y = ry; }
                    cbase += tot;
                }
                out4[(size_t)p * 8 + lp] = o;
            }
        }
    }

    // ---- overflow tail (MODE 0): ~zero cost when empty ----
    if constexpr (MODE == 0) {
        unsigned ovfn = *ovfcnt;
        if (ovfn > (unsigned)ovfl_cap) ovfn = (unsigned)ovfl_cap;
        for (unsigned u = blockIdx.x * 512u + threadIdx.x; u < ovfn;
             u += 4096u * 512u)
            point_direct(x, tab, out4, ovfl[u]);
    }
}

// Fallback (R1) if ws too small.
__global__ __launch_bounds__(256, 8)
void k_fallback(const float* __restrict__ x, const float2* __restrict__ tab,
                float2* __restrict__ out, int total) {
    int tid = blockIdx.x * 256 + threadIdx.x;
    if (tid >= total) return;
    int p = tid >> 4, l = tid & 15;
    float r = c_res[l];
    float s0 = x[3*p] * r, s1 = x[3*p+1] * r, s2 = x[3*p+2] * r;
    float f0 = floorf(s0), f1 = floorf(s1), f2 = floorf(s2);
    float d0 = s0 - f0, d1 = s1 - f1, d2 = s2 - f2;
    unsigned A0 = (unsigned)(int)f0, B0 = (unsigned)(int)ceilf(s0);
    unsigned A1 = (unsigned)(int)f1 * PRIME1, B1 = (unsigned)(int)ceilf(s1) * PRIME1;
    unsigned A2 = (unsigned)(int)f2 * PRIME2, B2 = (unsigned)(int)ceilf(s2) * PRIME2;
    unsigned h0=(A0^A1^A2)&TMASK, h1=(B0^A1^A2)&TMASK, h2=(A0^B1^A2)&TMASK;
    unsigned h3=(A0^A1^B2)&TMASK, h4=(B0^B1^A2)&TMASK, h5=(B0^A1^B2)&TMASK;
    unsigned h6=(A0^B1^B2)&TMASK, h7=(B0^B1^B2)&TMASK;
    float2 v0=tab[h0],v1=tab[h1],v2=tab[h2],v3=tab[h3];
    float2 v4=tab[h4],v5=tab[h5],v6=tab[h6],v7=tab[h7];
    float u0=1.f-d0,u1=1.f-d1,u2=1.f-d2;
    float ex = v0.x*(u0*u1*u2), ey = v0.y*(u0*u1*u2);
    ex += v1.x*(d0*u1*u2); ey += v1.y*(d0*u1*u2);
    ex += v2.x*(u0*d1*u2); ey += v2.y*(u0*d1*u2);
    ex += v3.x*(u0*u1*d2); ey += v3.y*(u0*u1*d2);
    ex += v4.x*(d0*d1*u2); ey += v4.y*(d0*d1*u2);
    ex += v5.x*(d0*u1*d2); ey += v5.y*(d0*u1*d2);
    ex += v6.x*(u0*d1*d2); ey += v6.y*(u0*d1*d2);
    ex += v7.x*(d0*d1*d2); ey += v7.y*(d0*d1*d2);
    float2 o; o.x = ex; o.y = ey; out[tid] = o;
}

extern "C" void kernel_launch(void* const* d_in, const int* in_sizes, int n_in,
                              void* d_out, int out_size, void* d_ws, size_t ws_size,
                              hipStream_t stream)
{
    const float*  x   = (const float*)d_in[0];
    const float2* tab = (const float2*)d_in[1];
    int npts = in_sizes[0] / 3;

    // ---- Tier A: fixed-capacity buckets, 1 aux kernel ----
    {
        size_t off_cnt  = 0;                                       // 16 KB
        size_t off_ovfc = off_cnt + (size_t)NBUCKET * 4;           // 64 B slot
        size_t off_ovfl = (off_ovfc + 64 + 63) & ~(size_t)63;      // npts*4
        size_t off_xs   = (off_ovfl + (size_t)npts * 4 + 255) & ~(size_t)255;
        if (ws_size > off_xs) {
            size_t avail = ws_size - off_xs;
            long long capll = (long long)(avail / ((size_t)NBUCKET * 16));
            int cap = (int)(capll > 512 ? 512 : capll);
            int mean = npts / NBUCKET + 1;
            if (cap >= mean + (mean + 3) / 4 + 64) {
                unsigned* cnt    = (unsigned*)((char*)d_ws + off_cnt);
                unsigned* ovfc   = (unsigned*)((char*)d_ws + off_ovfc);
                unsigned* ovfl   = (unsigned*)((char*)d_ws + off_ovfl);
                float4*   xs     = (float4*)  ((char*)d_ws + off_xs);

                hipMemsetAsync((char*)d_ws + off_cnt, 0,
                               (size_t)NBUCKET * 4 + 64, stream);
                k_scat1 <<<NB, 1024, 0, stream>>>(x, cnt, ovfc, ovfl, xs,
                                                  npts, cap, npts);
                k_main<0><<<NBUCKET, 512, 0, stream>>>(xs, x, nullptr, nullptr,
                                                       tab, (float4*)d_out,
                                                       cnt, ovfc, ovfl,
                                                       cap, npts);
                return;
            }
        }
    }

    // ---- Tier B: perm-only path (R9, ~8.3 MB ws) ----
    {
        size_t off_grpsum = 0;                                        // 256 KB
        size_t off_cnt    = off_grpsum + (size_t)NGRP * NBUCKET * 4;  // 4 MB
        size_t off_starts = off_cnt    + (size_t)NB * NBUCKET * 4;
        size_t off_perm   = (off_starts + (size_t)(NBUCKET + 1) * 4 + 63)
                            & ~(size_t)63;
        size_t need       = off_perm + (size_t)npts * 4;
        if (ws_size >= need) {
            unsigned* grpsum = (unsigned*)((char*)d_ws + off_grpsum);
            unsigned* cnt    = (unsigned*)((char*)d_ws + off_cnt);
            unsigned* starts = (unsigned*)((char*)d_ws + off_starts);
            unsigned* perm   = (unsigned*)((char*)d_ws + off_perm);

            hipMemsetAsync(grpsum, 0, (size_t)NGRP * NBUCKET * 4, stream);
            k_histA   <<<NB, 1024, 0, stream>>>(x, cnt, grpsum, npts);
            k_scatB   <<<NB, 1024, 0, stream>>>(x, cnt, grpsum, starts,
                                                perm, npts);
            k_main<1> <<<NBUCKET, 512, 0, stream>>>(nullptr, x, perm, starts,
                                                    tab, (float4*)d_out,
                                                    nullptr, nullptr, nullptr,
                                                    0, 0);
            return;
        }
    }

    // ---- fallback ----
    int total = npts * 16;
    k_fallback<<<(total + 255) / 256, 256, 0, stream>>>(
        x, tab, (float2*)d_out, total);
}